// Round 8
// baseline (264.420 us; speedup 1.0000x reference)
//
#include <hip/hip_runtime.h>

// LIF neuron scan: v = v*0.5 + x[t]; s = (v - 0.5 > 0); v -= s*0.5
// Round 7 -> 8: clean A/B. R7's regression (97.5 -> 255 us) was the
// nontemporal stores: WRITE_SIZE 205 -> 547 MB (NT bypasses L2 merging ->
// partial-sector RMW at HBM), FETCH also inflated. Revert to regular cached
// stores. KEEP the barrier-free structure (the other R7 change, untested in
// isolation): 256-thread blocks, wave-private 13.3KB LDS tiles, zero
// __syncthreads -> no vmcnt(0)/lgkmcnt(0) drain points; wave's in-order DS
// pipe provides all ordering. Tests R5's barrier-drain theory cleanly.

#define T_STEPS 100
#define T_VEC   25      // float4 per row
#define WROWS   64      // rows per wave
#define HROWS   32      // rows per bounce stage
#define SLOTS   26      // float4 slots per LDS row (25 + 1 pad)
#define WAVES   4       // waves per block
#define DECAY   0.5f
#define VTH     0.5f

typedef float vfloat4 __attribute__((ext_vector_type(4)));

__device__ __forceinline__ int swz(int c4, int row) {
    // XOR low 3 bits for c4 in [0,24); c4==24 stays (in range). Per fixed c4,
    // row-groups of 8 map bijectively -> minimal bank aliasing for b128 ops.
    return (c4 < 24) ? (c4 ^ (row & 7)) : c4;
}

__global__ __launch_bounds__(256, 3) void lif_kernel(const float* __restrict__ x,
                                                     float* __restrict__ out,
                                                     int n_rows) {
    __shared__ vfloat4 tile[WAVES][HROWS * SLOTS];   // 53,248 B -> 3 blocks/CU

    const int lane = threadIdx.x & 63;
    const int wv   = threadIdx.x >> 6;
    const long long wid   = (long long)blockIdx.x * WAVES + wv;
    const long long row0  = wid * WROWS;
    const long long total_f4 = (long long)n_rows * T_VEC;

    vfloat4* tw = tile[wv];
    const vfloat4* __restrict__ xb = reinterpret_cast<const vfloat4*>(x);
    vfloat4* __restrict__ ob       = reinterpret_cast<vfloat4*>(out);

    vfloat4 buf[T_VEC];

    // ---- Input: per-wave two stages of {coalesced load -> LDS -> row grab}.
    // No barriers: wave-private tile, in-order DS + compiler lgkmcnt waits.
    #pragma unroll
    for (int stage = 0; stage < 2; ++stage) {
        const long long gbase = (row0 + stage * HROWS) * T_VEC;
        #pragma unroll
        for (int k = 0; k < 13; ++k) {
            int f = k * 64 + lane;                 // 0..831
            if (f < HROWS * T_VEC && gbase + f < total_f4) {
                vfloat4 w = xb[gbase + f];         // full-line coalesced
                int r  = f / T_VEC;
                int c4 = f % T_VEC;
                tw[r * SLOTS + swz(c4, r)] = w;
            }
        }
        if ((lane >> 5) == stage) {                // owning half-wave grabs rows
            const int r = lane & (HROWS - 1);
            #pragma unroll
            for (int j = 0; j < T_VEC; ++j)
                buf[j] = tw[r * SLOTS + swz(j, r)];
        }
    }

    // ---- Compute: 100-step LIF recurrence entirely in registers ----
    if (row0 + lane < n_rows) {
        float v = 0.0f;
        #pragma unroll
        for (int j = 0; j < T_VEC; ++j) {
            float xs[4] = {buf[j].x, buf[j].y, buf[j].z, buf[j].w};
            float ss[4];
            #pragma unroll
            for (int k = 0; k < 4; ++k) {
                // v*0.5 exact (pow2); s*0.5 in {0,0.5} exact -> bitwise == ref.
                v = v * DECAY + xs[k];
                float sk = (v - VTH > 0.0f) ? 1.0f : 0.0f;
                v -= sk * VTH;
                ss[k] = sk;
            }
            buf[j].x = ss[0]; buf[j].y = ss[1]; buf[j].z = ss[2]; buf[j].w = ss[3];
        }
    }

    // ---- Output: per-wave two stages of {row write -> coalesced store}.
    // Still no barriers; WAR on tile is ordered by the wave's in-order DS pipe.
    #pragma unroll
    for (int stage = 0; stage < 2; ++stage) {
        if ((lane >> 5) == stage) {
            const int r = lane & (HROWS - 1);
            #pragma unroll
            for (int j = 0; j < T_VEC; ++j)
                tw[r * SLOTS + swz(j, r)] = buf[j];
        }
        const long long gbase = (row0 + stage * HROWS) * T_VEC;
        #pragma unroll
        for (int k = 0; k < 13; ++k) {
            int f = k * 64 + lane;
            if (f < HROWS * T_VEC && gbase + f < total_f4) {
                int r  = f / T_VEC;
                int c4 = f % T_VEC;
                ob[gbase + f] = tw[r * SLOTS + swz(c4, r)];
            }
        }
    }
}

extern "C" void kernel_launch(void* const* d_in, const int* in_sizes, int n_in,
                              void* d_out, int out_size, void* d_ws, size_t ws_size,
                              hipStream_t stream) {
    const float* x = (const float*)d_in[0];
    float* out = (float*)d_out;

    int n_rows = in_sizes[0] / T_STEPS;                 // 32 * 16384 = 524288
    int rows_per_block = WROWS * WAVES;                 // 256
    int grid = (n_rows + rows_per_block - 1) / rows_per_block;   // 2048

    lif_kernel<<<grid, 256, 0, stream>>>(x, out, n_rows);
}

// Round 10
// 118.250 us; speedup vs baseline: 2.2361x; 2.2361x over previous
//
#include <hip/hip_runtime.h>

// LIF neuron scan: v = v*0.5 + x[t]; s = (v - 0.5 > 0); v -= s*0.5
// Round 9 -> 10: same as R9 (fixing the compile error: stray forward macro
// reference). Theory: R7/R8's 550MB WRITE / 291MB FETCH at VGPR=84 while
// needing 100 live VGPRs for buf[25] = scratch spill traffic through L2/HBM
// (R4/R5's shared ~97.5us plateau, same disease milder). Serial state is only
// `v`; spikes are BINARY:
//  - compute in 5 chunks of 5 float4 (direct strided loads, L3-served),
//    packing spike bits into 4 u32 (live state ~30 VGPRs, no spill)
//  - one ds_write_b128/lane (row's 100 bits, 16B), LDS = 1KB, conflict-free
//  - ONE __syncthreads in the whole kernel
//  - 25 coalesced full-line wave-stores, expanding nibbles -> 0.0f/1.0f
//    (the exact store pattern that gave WRITE_SIZE == 204800 KB in R3).

#define T_STEPS 100
#define T_VEC   25      // float4 per row
#define CHUNK   5       // float4 per compute chunk
#define NCHUNK  5
#define ROWS    64      // rows per block == blockDim.x (one wave)
#define DECAY   0.5f
#define VTH     0.5f

typedef float vfloat4 __attribute__((ext_vector_type(4)));

__global__ __launch_bounds__(64, 6) void lif_kernel(const float* __restrict__ x,
                                                    float* __restrict__ out,
                                                    int n_rows) {
    __shared__ unsigned int tile[ROWS * 4];   // 1KB: 100 spike bits per row

    const int lane = threadIdx.x;             // block = 64 = one wave
    const long long row0 = (long long)blockIdx.x * ROWS;
    const long long my_row = row0 + lane;

    unsigned int pk0 = 0, pk1 = 0, pk2 = 0, pk3 = 0;

    // ---- Compute: chunked, ~30 live VGPRs, spikes packed to bits ----
    if (my_row < n_rows) {
        const vfloat4* __restrict__ xr =
            reinterpret_cast<const vfloat4*>(x) + my_row * T_VEC;
        float v = 0.0f;
        #pragma unroll
        for (int c = 0; c < NCHUNK; ++c) {
            vfloat4 xs[CHUNK];
            #pragma unroll
            for (int j = 0; j < CHUNK; ++j) xs[j] = xr[c * CHUNK + j];
            #pragma unroll
            for (int j = 0; j < CHUNK; ++j) {
                #pragma unroll
                for (int k = 0; k < 4; ++k) {
                    // v*0.5 exact (pow2); conditional -0.5 exact -> bitwise == ref.
                    v = v * DECAY + xs[j][k];
                    bool sb = (v - VTH > 0.0f);
                    v -= sb ? VTH : 0.0f;
                    unsigned int bit = sb ? 1u : 0u;
                    const int b = c * 20 + j * 4 + k;   // compile-time 0..99
                    if (b < 32)      pk0 |= bit << b;
                    else if (b < 64) pk1 |= bit << (b - 32);
                    else if (b < 96) pk2 |= bit << (b - 64);
                    else             pk3 |= bit << (b - 96);
                }
            }
        }
    }

    // ---- One b128 LDS write per lane (16B of packed bits), one barrier ----
    {
        uint4 w; w.x = pk0; w.y = pk1; w.z = pk2; w.w = pk3;
        reinterpret_cast<uint4*>(tile)[lane] = w;
    }
    __syncthreads();

    // ---- Expand + coalesced full-line stores: 25 wave-instructions ----
    vfloat4* __restrict__ ob = reinterpret_cast<vfloat4*>(out);
    const long long gf0 = row0 * T_VEC;
    const long long total_f4 = (long long)n_rows * T_VEC;
    #pragma unroll
    for (int i = 0; i < T_VEC; ++i) {
        int f = i * 64 + lane;                 // 0..1599
        long long g = gf0 + f;
        if (g < total_f4) {
            int r  = f / T_VEC;                // magic-mul
            int c4 = f % T_VEC;
            unsigned int word = tile[r * 4 + (c4 >> 3)];   // broadcast-heavy
            int shift = (c4 & 7) * 4;
            unsigned int nib = (word >> shift) & 0xFu;
            vfloat4 s;
            s.x = (nib & 1u) ? 1.0f : 0.0f;
            s.y = (nib & 2u) ? 1.0f : 0.0f;
            s.z = (nib & 4u) ? 1.0f : 0.0f;
            s.w = (nib & 8u) ? 1.0f : 0.0f;
            ob[g] = s;
        }
    }
}

extern "C" void kernel_launch(void* const* d_in, const int* in_sizes, int n_in,
                              void* d_out, int out_size, void* d_ws, size_t ws_size,
                              hipStream_t stream) {
    const float* x = (const float*)d_in[0];
    float* out = (float*)d_out;

    int n_rows = in_sizes[0] / T_STEPS;         // 32 * 16384 = 524288
    int grid = (n_rows + ROWS - 1) / ROWS;      // 8192

    lif_kernel<<<grid, ROWS, 0, stream>>>(x, out, n_rows);
}

// Round 11
// 89.555 us; speedup vs baseline: 2.9526x; 1.3204x over previous
//
#include <hip/hip_runtime.h>

// LIF neuron scan: v = v*0.5 + x[t]; s = (v - 0.5 > 0); v -= s*0.5
// Round 10 -> 11: fix READ REQUEST RATE. R10 was clean on every byte counter
// (WRITE exactly 204800 KB, FETCH 161 MB, VGPR 32, 0 conflicts) yet slower
// than R4/5 and stuck at 2.9 TB/s: per-lane 400B-strided float4 reads cost 64
// line-requests per wave-load (16B used / 64B line) vs 8 sector-requests for
// a coalesced load -> 8x tax on the L1/L2 request path. Fix: coalesced
// full-line wave loads -> reg batches -> XOR-swizzled LDS tile -> per-lane
// b128 row walk (5 live f4, no spill) -> R10's bit-pack -> R10's expansion
// store. 1 wave/block, LDS 26.6 KB (6 blocks/CU, 25KB loads in flight each).

#define T_STEPS 100
#define T_VEC   25      // float4 per row
#define ROWS    64      // rows per block == blockDim.x (one wave)
#define RSTRIDE 100     // dwords per LDS row (400 B, keeps b128 16B-aligned)
#define DECAY   0.5f
#define VTH     0.5f

typedef float vfloat4 __attribute__((ext_vector_type(4)));

__device__ __forceinline__ int eswz(int r) { return (r ^ (r >> 3)) & 7; }
// dword offset of row r's f4-chunk c; XOR granule swizzle breaks the
// stride-100 (= 4 bank-quads) row aliasing: lanes r and r+8 get different
// quads via the r>>3 term. c==24 left unswizzled (stays in range).
__device__ __forceinline__ int slot(int r, int c) {
    int cs = (c < 24) ? (c ^ eswz(r)) : 24;
    return r * RSTRIDE + cs * 4;
}

__global__ __launch_bounds__(64) void lif_kernel(const float* __restrict__ x,
                                                 float* __restrict__ out,
                                                 int n_rows) {
    __shared__ float tile[ROWS * RSTRIDE];     // 25,600 B
    __shared__ unsigned int bits[ROWS * 4];    //  1,024 B -> 26.6 KB total

    const int lane = threadIdx.x;
    const long long row0 = (long long)blockIdx.x * ROWS;
    const long long gf0 = row0 * T_VEC;
    const long long total_f4 = (long long)n_rows * T_VEC;

    const vfloat4* __restrict__ xb = reinterpret_cast<const vfloat4*>(x);

    // ---- Stage: coalesced global loads (full 128B sectors) -> swizzled LDS.
    // Two reg batches; loads within (and across) batches are independent, so
    // the compiler can keep up to 25 KB in flight per wave.
    {
        vfloat4 st[13];
        #pragma unroll
        for (int k = 0; k < 13; ++k) {
            long long g = gf0 + k * 64 + lane;
            vfloat4 z = {0.0f, 0.0f, 0.0f, 0.0f};
            st[k] = (g < total_f4) ? xb[g] : z;
        }
        #pragma unroll
        for (int k = 0; k < 13; ++k) {
            int f = k * 64 + lane;                 // 0..831
            int r = f / T_VEC, c = f % T_VEC;      // magic-mul
            *reinterpret_cast<vfloat4*>(&tile[slot(r, c)]) = st[k];
        }
    }
    {
        vfloat4 st[12];
        #pragma unroll
        for (int k = 0; k < 12; ++k) {
            long long g = gf0 + (13 + k) * 64 + lane;
            vfloat4 z = {0.0f, 0.0f, 0.0f, 0.0f};
            st[k] = (g < total_f4) ? xb[g] : z;
        }
        #pragma unroll
        for (int k = 0; k < 12; ++k) {
            int f = (13 + k) * 64 + lane;          // 832..1599
            int r = f / T_VEC, c = f % T_VEC;
            *reinterpret_cast<vfloat4*>(&tile[slot(r, c)]) = st[k];
        }
    }
    // 1-wave block: in-order DS pipe + compiler lgkmcnt tracking order the
    // ds_writes before the dependent ds_reads below; no barrier needed here.

    // ---- Walk own row from LDS chunk-wise, pack spike bits (no spill) ----
    unsigned int pk0 = 0, pk1 = 0, pk2 = 0, pk3 = 0;
    {
        float v = 0.0f;
        #pragma unroll
        for (int c = 0; c < T_VEC; ++c) {
            vfloat4 xs = *reinterpret_cast<const vfloat4*>(&tile[slot(lane, c)]);
            #pragma unroll
            for (int k = 0; k < 4; ++k) {
                // v*0.5 exact (pow2); conditional -0.5 exact -> bitwise == ref.
                v = v * DECAY + xs[k];
                bool sb = (v - VTH > 0.0f);
                v -= sb ? VTH : 0.0f;
                unsigned int bit = sb ? 1u : 0u;
                const int b = c * 4 + k;           // compile-time 0..99
                if (b < 32)      pk0 |= bit << b;
                else if (b < 64) pk1 |= bit << (b - 32);
                else if (b < 96) pk2 |= bit << (b - 64);
                else             pk3 |= bit << (b - 96);
            }
        }
    }

    // ---- One b128 bits write per lane, one (1-wave, cheap) barrier ----
    {
        uint4 w; w.x = pk0; w.y = pk1; w.z = pk2; w.w = pk3;
        reinterpret_cast<uint4*>(bits)[lane] = w;
    }
    __syncthreads();

    // ---- Expand + coalesced full-line stores (R10: 0 conflicts, exact) ----
    vfloat4* __restrict__ ob = reinterpret_cast<vfloat4*>(out);
    #pragma unroll
    for (int i = 0; i < T_VEC; ++i) {
        int f = i * 64 + lane;                     // 0..1599
        long long g = gf0 + f;
        if (g < total_f4) {
            int r  = f / T_VEC;
            int c4 = f % T_VEC;
            unsigned int word = bits[r * 4 + (c4 >> 3)];   // broadcast-heavy
            int shift = (c4 & 7) * 4;
            unsigned int nib = (word >> shift) & 0xFu;
            vfloat4 s;
            s.x = (nib & 1u) ? 1.0f : 0.0f;
            s.y = (nib & 2u) ? 1.0f : 0.0f;
            s.z = (nib & 4u) ? 1.0f : 0.0f;
            s.w = (nib & 8u) ? 1.0f : 0.0f;
            ob[g] = s;
        }
    }
}

extern "C" void kernel_launch(void* const* d_in, const int* in_sizes, int n_in,
                              void* d_out, int out_size, void* d_ws, size_t ws_size,
                              hipStream_t stream) {
    const float* x = (const float*)d_in[0];
    float* out = (float*)d_out;

    int n_rows = in_sizes[0] / T_STEPS;         // 32 * 16384 = 524288
    int grid = (n_rows + ROWS - 1) / ROWS;      // 8192

    lif_kernel<<<grid, ROWS, 0, stream>>>(x, out, n_rows);
}